// Round 6
// baseline (199.894 us; speedup 1.0000x reference)
//
#include <hip/hip_runtime.h>

// CTC loss (blank=0, mean reduction, zero_infinity) for
// B=64, T=1024, K=512, L=100  ->  S = 2L+1 = 201 extended states.
//
// FUSED single-pass design (round 6): one block per batch, 4 waves.
//   wave 0  = consumer: linear-domain ratio recursion (all cross-lane via
//             DPP on the VALU pipe), exact power-of-2 rescale every 4 steps
//             with the wave-max application deferred one window.
//   waves 1-3 = softmax-producers: per 16-row chunk each wave takes 5-6 raw
//             logit rows (2 x float4 per lane, register double-buffered,
//             issued 2 chunks ahead), computes row max + sum(exp) via DPP
//             reductions, accumulates lb = log2(512*p_blank) in a register,
//             stages the row in per-wave LDS scratch (alternating slot),
//             gathers the 100 target-class ratios r = p_lab/p_blank, and
//             writes the 104-float ratio row into the chunk's LDS buffer.
// Ratio formulation: factor prod_t p_blank out of all alpha states:
//   even states: a' = (sums);  odd states: a' = (sums) * r
//   logl/ln2 = log2(beta_end) + eacc + sum_t lb(t) - T*9.
// This removes the separate softmax kernel and its 27 MB intermediate
// entirely; softmax VALU work hides under the latency-bound recursion.

#define TT 1024
#define BB 64
#define KK 512
#define LL 100
#define ROW 104
#define CH 16                 // rows per chunk
#define NCH 64                // chunks (TT/CH)
#define CHF (CH * ROW)        // 1664 floats per chunk buffer

static constexpr float L2E = 1.44269504088896340736f;
static constexpr float LN2 = 0.69314718055994530942f;

// lane i <- lane i-1, lane 0 <- 0.0f  (v_mov_b32_dpp wave_shr:1, VALU pipe)
__device__ __forceinline__ float dpp_shr1_z(float x) {
  return __builtin_bit_cast(float,
      __builtin_amdgcn_update_dpp(0, __builtin_bit_cast(int, x),
                                  0x138, 0xf, 0xf, true));
}

// wave64 max via DPP (row_shr 1/2/4/8 + row_bcast15/31) + v_readlane(63).
// VALU-pipe only. Valid for x >= 0 (bound_ctrl 0-fill).
__device__ __forceinline__ float wave_max_dpp(float v) {
#define DPPMAX(C)                                                          \
  v = fmaxf(v, __builtin_bit_cast(float, __builtin_amdgcn_update_dpp(      \
                   0, __builtin_bit_cast(int, v), C, 0xf, 0xf, true)))
  DPPMAX(0x111); DPPMAX(0x112); DPPMAX(0x114); DPPMAX(0x118);
  DPPMAX(0x142); DPPMAX(0x143);
#undef DPPMAX
  return __builtin_bit_cast(float,
      __builtin_amdgcn_readlane(__builtin_bit_cast(int, v), 63));
}

// wave64 sum via the same ladder (0-fill adds 0 -> exact).
__device__ __forceinline__ float wave_sum_dpp(float v) {
#define DPPADD(C)                                                          \
  v = v + __builtin_bit_cast(float, __builtin_amdgcn_update_dpp(           \
              0, __builtin_bit_cast(int, v), C, 0xf, 0xf, true))
  DPPADD(0x111); DPPADD(0x112); DPPADD(0x114); DPPADD(0x118);
  DPPADD(0x142); DPPADD(0x143);
#undef DPPADD
  return __builtin_bit_cast(float,
      __builtin_amdgcn_readlane(__builtin_bit_cast(int, v), 63));
}

__global__ __launch_bounds__(256) void k_ctc(const float* __restrict__ logits,
                                             const int* __restrict__ targets,
                                             float* __restrict__ per) {
  const int b = blockIdx.x;
  const int tid = threadIdx.x;
  const int lane = tid & 63;

  __shared__ float ratio[4][CHF];     // 26.6 KB: staged ratio rows
  __shared__ float scratch[3][2][KK]; // 12 KB: per-producer row scratch
  __shared__ float lbPart[3];

  if (tid >= 64) {
    // ------------- producers: waves 1-3 (softmax + gather) -------------
    const int w = (tid >> 6) - 1;               // 0..2
    const int rowStart = (w == 0) ? 0 : (w == 1) ? 6 : 11;
    const int nRows = (w == 0) ? 6 : 5;
    const float* xbase = logits + (size_t)b * TT * KK;

    int2 tc = {0, 0};                           // my 2 target classes
    if (lane >= 1 && lane <= 50)
      tc = *reinterpret_cast<const int2*>(targets + b * LL + 2 * (lane - 1));

    float4 rA[6][2], rB[6][2];
    float sumLb = 0.0f;

#define P_ISSUE(SET, CHN)                                                  \
    do {                                                                   \
      _Pragma("unroll") for (int k = 0; k < 6; ++k) if (k < nRows) {       \
        const float4* gp_ = reinterpret_cast<const float4*>(               \
            xbase + (size_t)((CHN) * CH + rowStart + k) * KK);             \
        SET[k][0] = gp_[lane];                                             \
        SET[k][1] = gp_[lane + 64];                                        \
      }                                                                    \
    } while (0)

#define P_PROC(SET, CHN)                                                   \
    do {                                                                   \
      float* rb_ = ratio[(CHN) & 3];                                       \
      _Pragma("unroll") for (int k = 0; k < 6; ++k) if (k < nRows) {       \
        const float4 v0 = SET[k][0], v1 = SET[k][1];                       \
        float* sc_ = scratch[w][k & 1];                                    \
        reinterpret_cast<float4*>(sc_)[lane] = v0;                         \
        reinterpret_cast<float4*>(sc_)[lane + 64] = v1;                    \
        float m_ = fmaxf(fmaxf(fmaxf(v0.x, v0.y), fmaxf(v0.z, v0.w)),      \
                         fmaxf(fmaxf(v1.x, v1.y), fmaxf(v1.z, v1.w)));     \
        m_ = wave_max_dpp(m_);                                             \
        const float mm_ = m_ * L2E;                                        \
        float e_ = exp2f(fmaf(v0.x, L2E, -mm_)) +                          \
                   exp2f(fmaf(v0.y, L2E, -mm_)) +                          \
                   exp2f(fmaf(v0.z, L2E, -mm_)) +                          \
                   exp2f(fmaf(v0.w, L2E, -mm_)) +                          \
                   exp2f(fmaf(v1.x, L2E, -mm_)) +                          \
                   exp2f(fmaf(v1.y, L2E, -mm_)) +                          \
                   exp2f(fmaf(v1.z, L2E, -mm_)) +                          \
                   exp2f(fmaf(v1.w, L2E, -mm_));                           \
        e_ = wave_sum_dpp(e_);                                             \
        const float xb_ = __builtin_bit_cast(float,                        \
            __builtin_amdgcn_readlane(__builtin_bit_cast(int, v0.x), 0));  \
        sumLb += (xb_ - m_) * L2E + 9.0f - log2f(e_);                      \
        float2 o_ = {0.0f, 0.0f};                                          \
        if (lane >= 1 && lane <= 50) {                                     \
          o_.x = exp2f((sc_[tc.x] - xb_) * L2E);                           \
          o_.y = exp2f((sc_[tc.y] - xb_) * L2E);                           \
        }                                                                  \
        if (lane < 52)                                                     \
          reinterpret_cast<float2*>(rb_ + (rowStart + k) * ROW)[lane] = o_;\
      }                                                                    \
    } while (0)

    P_ISSUE(rA, 0);
    P_ISSUE(rB, 1);
    P_PROC(rA, 0);
    __syncthreads();
    for (int c = 0; c < NCH; ++c) {
      if (c + 2 < NCH) {
        if (c & 1) P_ISSUE(rB, c + 2);
        else       P_ISSUE(rA, c + 2);
      }
      if (c + 1 < NCH) {
        if (c & 1) P_PROC(rA, c + 1);
        else       P_PROC(rB, c + 1);
      }
      __syncthreads();
    }
    if (lane == 0) lbPart[w] = sumLb;
    __syncthreads();
    return;
#undef P_ISSUE
#undef P_PROC
  }

  // ------------------- consumer: wave 0 (recursion) ---------------------
  const int i = tid;                            // lane, states 4i..4i+3
  const int* tg = targets + b * LL;

  int offlab = 2 + 2 * i;                       // ratio float2 offset
  if (offlab > 102) offlab = 102;               // pad lanes -> zeros

  const int l0 = 2 * i, l1 = 2 * i + 1;
  float mA = 0.0f, mB = 0.0f;
  if (i > 0 && l0 <= LL - 1) mA = (tg[l0] != tg[l0 - 1]) ? 1.0f : 0.0f;
  if (l1 <= LL - 1)          mB = (tg[l1] != tg[l1 - 1]) ? 1.0f : 0.0f;
  float mBp = __shfl_up(mB, 1);                 // neighbor's mB (init only)
  if (i == 0) mBp = 0.0f;

  // virtual init: beta_{-1} = delta on lane 0; 1024 uniform steps follow.
  float a0 = (i == 0) ? 1.0f : 0.0f;
  float a1 = 0.0f, a2 = 0.0f, a3 = 0.0f;
  int eacc = 0;
  float mpend = 1.0f;                           // deferred-rescale max

#define RESCALE()                                                          \
  do {                                                                     \
    if (mpend > 0.0f) {                                                    \
      const int E_ = (int)((__float_as_uint(mpend) >> 23) & 255) - 127;    \
      const float sc_ = __uint_as_float((unsigned)(127 - E_) << 23);       \
      a0 *= sc_; a1 *= sc_; a2 *= sc_; a3 *= sc_;                          \
      eacc += E_;                                                          \
    }                                                                      \
    mpend = wave_max_dpp(fmaxf(fmaxf(a0, a1), fmaxf(a2, a3)));             \
  } while (0)

  __syncthreads();                              // matches producer prologue
  for (int c = 0; c < NCH; ++c) {
    const float* Lp = ratio[c & 3] + offlab;
    float2 R[16];                               // chunk-top batched loads
    #pragma unroll
    for (int j = 0; j < 16; ++j)
      R[j] = *reinterpret_cast<const float2*>(Lp + j * ROW);
    #pragma unroll
    for (int pr = 0; pr < 8; ++pr) {            // 2 recursion steps / pair
      const float2 PL = R[2 * pr];
      const float2 QL = R[2 * pr + 1];

      const float A1 = dpp_shr1_z(a1);          // lane0 -> 0 (boundary)
      const float A2 = dpp_shr1_z(a2);
      const float A3 = dpp_shr1_z(a3);
      const float RYp = dpp_shr1_z(PL.y);       // neighbor's ratio

      // step t
      const float b0 = a0 + A3;                       // s=4i   (blank)
      const float b1 = (a0 + a1 + mA * A3) * PL.x;    // s=4i+1 (label 2i)
      const float b2 = a1 + a2;                       // s=4i+2 (blank)
      const float b3 = (a2 + a3 + mB * a1) * PL.y;    // s=4i+3 (label 2i+1)
      const float b3p = (A2 + A3 + mBp * A1) * RYp;   // neighbor's new a3
      // step t+1
      a0 = b0 + b3p;
      a1 = (b0 + b1 + mA * b3p) * QL.x;
      a2 = b1 + b2;
      a3 = (b2 + b3 + mB * b1) * QL.y;

      if (pr & 1) RESCALE();                    // every 4 steps
    }
    __syncthreads();
  }
#undef RESCALE

  __syncthreads();                              // producers publish lbPart

  // logl = log(beta[199] + beta[200]) + ...; 199 = lane49.a3, 200 = lane50.a0
  const float v199 = __shfl(a3, 49);
  const float v200 = __shfl(a0, 50);
  if (i == 0) {
    const float s4 = lbPart[0] + lbPart[1] + lbPart[2];
    const float s = v199 + v200;
    float loss = 0.0f;                          // zero_infinity
    if (s > 0.0f) {
      const float logl2 = log2f(s) + (float)eacc + s4 - (float)(TT * 9);
      loss = -(logl2 * LN2) / (float)LL;
    }
    per[b] = loss;
  }
}

__global__ __launch_bounds__(64) void k_mean(const float* __restrict__ per,
                                             float* __restrict__ out) {
  const int i = threadIdx.x;
  float v = per[i];
  #pragma unroll
  for (int d = 1; d < 64; d <<= 1) v += __shfl_xor(v, d);
  if (i == 0) out[0] = v * (1.0f / (float)BB);
}

extern "C" void kernel_launch(void* const* d_in, const int* in_sizes, int n_in,
                              void* d_out, int out_size, void* d_ws, size_t ws_size,
                              hipStream_t stream) {
  const float* logits = (const float*)d_in[0];   // (64, 1024, 512) f32
  const int* targets = (const int*)d_in[1];      // (64, 100) i32
  float* out = (float*)d_out;                    // scalar f32
  float* per = (float*)d_ws;                     // 64 f32

  hipLaunchKernelGGL(k_ctc, dim3(BB), dim3(256), 0, stream,
                     logits, targets, per);
  hipLaunchKernelGGL(k_mean, dim3(1), dim3(64), 0, stream, per, out);
}

// Round 7
// 76.752 us; speedup vs baseline: 2.6044x; 2.6044x over previous
//
#include <hip/hip_runtime.h>

// CTC loss (blank=0, mean reduction, zero_infinity) for
// B=64, T=1024, K=512, L=100  ->  S = 2L+1 = 201 extended states.
//
// Ratio formulation: factor prod_t p_blank(t) out of every alpha state.
//   even states: a' = (sums)          [no multiply]
//   odd  states: a' = (sums) * r      [r = p_lab / p_blank]
//   logl/ln2 = log2(beta_end) + eacc + sum_t lb(t) - T*9,
// where lb(t) = log2(512 * p_blank(t)) emitted per (b,t) by k_probs.
//
//  1) k_probs: per (b,t) row softmax over K=512 (one wave per row), emits
//     the 100 target ratios into glp rows (104 floats) + lb into lbArr.
//  2) k_ctc: linear-domain forward recursion, ONE WAVE per batch, no LDS,
//     no barriers (round-6 lesson: producer staging + per-chunk barriers
//     set the chunk period; consumer needs only 8 B/lane/row and glp is
//     L2/L3-resident). 16-row chunks in named register buffers, 3-buffer
//     ping-pong with 2-chunk slack, sched_barrier(0) after each issue
//     clause to prevent load sinking (round-2 failure mode). All
//     cross-lane traffic via DPP (VALU pipe; round-3 lesson: ds_bpermute
//     serializes the in-order DS queue onto the critical path).
//     Exact power-of-2 rescale every 4 steps, apply deferred one window.
//  3) k_mean: mean over the 64 per-batch losses.

#define TT 1024
#define BB 64
#define KK 512
#define LL 100
#define ROW 104
#define CH 16                 // rows per chunk
#define NCH 64                // chunks (TT/CH)

static constexpr float L2E = 1.44269504088896340736f;
static constexpr float LN2 = 0.69314718055994530942f;

// lane i <- lane i-1, lane 0 <- 0.0f  (v_mov_b32_dpp wave_shr:1, VALU pipe)
__device__ __forceinline__ float dpp_shr1_z(float x) {
  return __builtin_bit_cast(float,
      __builtin_amdgcn_update_dpp(0, __builtin_bit_cast(int, x),
                                  0x138, 0xf, 0xf, true));
}

// wave64 max via DPP (row_shr 1/2/4/8 + row_bcast15/31) + v_readlane(63).
// VALU-pipe only. Valid for x >= 0 (bound_ctrl 0-fill).
__device__ __forceinline__ float wave_max_dpp(float v) {
#define DPPMAX(C)                                                          \
  v = fmaxf(v, __builtin_bit_cast(float, __builtin_amdgcn_update_dpp(      \
                   0, __builtin_bit_cast(int, v), C, 0xf, 0xf, true)))
  DPPMAX(0x111); DPPMAX(0x112); DPPMAX(0x114); DPPMAX(0x118);
  DPPMAX(0x142); DPPMAX(0x143);
#undef DPPMAX
  return __builtin_bit_cast(float,
      __builtin_amdgcn_readlane(__builtin_bit_cast(int, v), 63));
}

__global__ __launch_bounds__(256) void k_probs(const float* __restrict__ logits,
                                               const int* __restrict__ targets,
                                               float* __restrict__ glp,
                                               float* __restrict__ lbArr) {
  const int wid = threadIdx.x >> 6;
  const int lane = threadIdx.x & 63;
  const int row = (blockIdx.x << 2) + wid;      // row = b*T + t
  const int b = row >> 10;                      // T = 1024
  const float* x = logits + (size_t)row * KK;

  __shared__ float sx[4][KK];

  const float4 v0 = reinterpret_cast<const float4*>(x)[lane];
  const float4 v1 = reinterpret_cast<const float4*>(x)[lane + 64];
  float4* sp = reinterpret_cast<float4*>(sx[wid]);
  sp[lane] = v0;
  sp[lane + 64] = v1;

  float m = fmaxf(fmaxf(fmaxf(v0.x, v0.y), fmaxf(v0.z, v0.w)),
                  fmaxf(fmaxf(v1.x, v1.y), fmaxf(v1.z, v1.w)));
  #pragma unroll
  for (int d = 1; d < 64; d <<= 1) m = fmaxf(m, __shfl_xor(m, d));

  float e = exp2f((v0.x - m) * L2E) + exp2f((v0.y - m) * L2E) +
            exp2f((v0.z - m) * L2E) + exp2f((v0.w - m) * L2E) +
            exp2f((v1.x - m) * L2E) + exp2f((v1.y - m) * L2E) +
            exp2f((v1.z - m) * L2E) + exp2f((v1.w - m) * L2E);
  #pragma unroll
  for (int d = 1; d < 64; d <<= 1) e += __shfl_xor(e, d);

  __syncthreads();
  const float xb = sx[wid][0];                  // blank logit

  if (lane < 52) {
    float2 o = {0.0f, 0.0f};
    if (lane >= 1 && lane <= 50) {
      const int* tg = targets + b * LL + (2 * lane - 2);
      const int2 c = *reinterpret_cast<const int2*>(tg);
      o.x = exp2f((sx[wid][c.x] - xb) * L2E);   // ratio p_lab / p_blank
      o.y = exp2f((sx[wid][c.y] - xb) * L2E);
    }
    reinterpret_cast<float2*>(glp + (size_t)row * ROW)[lane] = o;
  }
  // lb = log2(512 * p_blank) = (xb - m)*log2e + 9 - log2(sum exp)
  if (lane == 0) lbArr[row] = (xb - m) * L2E + 9.0f - log2f(e);
}

__global__ __launch_bounds__(64) void k_ctc(const float* __restrict__ glp,
                                            const float* __restrict__ lbArr,
                                            const int* __restrict__ targets,
                                            float* __restrict__ per) {
  const int b = blockIdx.x;
  const int i = threadIdx.x;                    // lane, states 4i..4i+3
  const int* tg = targets + b * LL;

  int offlab = 2 + 2 * i;                       // ratio float2 offset
  if (offlab > 102) offlab = 102;               // pad lanes -> zeros
  const float* gbase = glp + (size_t)b * TT * ROW + offlab;  // per-lane

  const int l0 = 2 * i, l1 = 2 * i + 1;
  float mA = 0.0f, mB = 0.0f;
  if (i > 0 && l0 <= LL - 1) mA = (tg[l0] != tg[l0 - 1]) ? 1.0f : 0.0f;
  if (l1 <= LL - 1)          mB = (tg[l1] != tg[l1 - 1]) ? 1.0f : 0.0f;
  float mBp = __shfl_up(mB, 1);                 // neighbor's mB (init only)
  if (i == 0) mBp = 0.0f;

  // virtual init: beta_{-1} = delta on lane 0; 1024 uniform steps follow.
  float a0 = (i == 0) ? 1.0f : 0.0f;
  float a1 = 0.0f, a2 = 0.0f, a3 = 0.0f;
  int eacc = 0;
  float mpend = 1.0f;                           // deferred-rescale max

  float2 RA[16], RB[16], RC[16];                // 3-buffer ping-pong

#define ISSUE(BUF, CHN)                                                    \
  do {                                                                     \
    _Pragma("unroll") for (int j = 0; j < 16; ++j)                         \
      BUF[j] = *reinterpret_cast<const float2*>(                           \
          gbase + (size_t)((CHN) * CH + j) * ROW);                         \
    __builtin_amdgcn_sched_barrier(0);                                     \
  } while (0)

#define RESCALE()                                                          \
  do {                                                                     \
    if (mpend > 0.0f) {                                                    \
      const int E_ = (int)((__float_as_uint(mpend) >> 23) & 255) - 127;    \
      const float sc_ = __uint_as_float((unsigned)(127 - E_) << 23);       \
      a0 *= sc_; a1 *= sc_; a2 *= sc_; a3 *= sc_;                          \
      eacc += E_;                                                          \
    }                                                                      \
    mpend = wave_max_dpp(fmaxf(fmaxf(a0, a1), fmaxf(a2, a3)));             \
  } while (0)

#define COMPUTE(BUF)                                                       \
  do {                                                                     \
    _Pragma("unroll") for (int pr = 0; pr < 8; ++pr) {                     \
      const float2 PL = BUF[2 * pr];                                       \
      const float2 QL = BUF[2 * pr + 1];                                   \
      const float A1 = dpp_shr1_z(a1);          /* lane0 -> 0 */           \
      const float A2 = dpp_shr1_z(a2);                                     \
      const float A3 = dpp_shr1_z(a3);                                     \
      const float RYp = dpp_shr1_z(PL.y);       /* neighbor's ratio */     \
      const float b0 = a0 + A3;                                            \
      const float b1 = (a0 + a1 + mA * A3) * PL.x;                         \
      const float b2 = a1 + a2;                                            \
      const float b3 = (a2 + a3 + mB * a1) * PL.y;                         \
      const float b3p = (A2 + A3 + mBp * A1) * RYp;                        \
      a0 = b0 + b3p;                                                       \
      a1 = (b0 + b1 + mA * b3p) * QL.x;                                    \
      a2 = b1 + b2;                                                        \
      a3 = (b2 + b3 + mB * b1) * QL.y;                                     \
      if (pr & 1) RESCALE();                    /* every 4 steps */        \
    }                                                                      \
  } while (0)

#define CHUNK(BUF, PFC, PFBUF)                                             \
  do {                                                                     \
    if ((PFC) < NCH) ISSUE(PFBUF, PFC);                                    \
    COMPUTE(BUF);                                                          \
  } while (0)

  ISSUE(RA, 0);
  ISSUE(RB, 1);
  for (int c = 0; c < 63; c += 3) {             // computes chunks 0..62
    CHUNK(RA, c + 2, RC);
    CHUNK(RB, c + 3, RA);
    CHUNK(RC, c + 4, RB);
  }
  COMPUTE(RA);                                  // chunk 63 (issued at c=60)
#undef ISSUE
#undef RESCALE
#undef COMPUTE
#undef CHUNK

  // epilogue: sum lb over t (coalesced float4 reads), wave-reduce.
  float s4 = 0.0f;
  {
    const float4* lbv = reinterpret_cast<const float4*>(lbArr + (size_t)b * TT);
    #pragma unroll
    for (int j = 0; j < 4; ++j) {
      const float4 v = lbv[i + 64 * j];
      s4 += (v.x + v.y) + (v.z + v.w);
    }
    #pragma unroll
    for (int d = 1; d < 64; d <<= 1) s4 += __shfl_xor(s4, d);
  }

  // logl = log(beta[199] + beta[200]) + ...; 199 = lane49.a3, 200 = lane50.a0
  const float v199 = __shfl(a3, 49);
  const float v200 = __shfl(a0, 50);
  if (i == 0) {
    const float s = v199 + v200;
    float loss = 0.0f;                          // zero_infinity
    if (s > 0.0f) {
      const float logl2 = log2f(s) + (float)eacc + s4 - (float)(TT * 9);
      loss = -(logl2 * LN2) / (float)LL;
    }
    per[b] = loss;
  }
}

__global__ __launch_bounds__(64) void k_mean(const float* __restrict__ per,
                                             float* __restrict__ out) {
  const int i = threadIdx.x;
  float v = per[i];
  #pragma unroll
  for (int d = 1; d < 64; d <<= 1) v += __shfl_xor(v, d);
  if (i == 0) out[0] = v * (1.0f / (float)BB);
}

extern "C" void kernel_launch(void* const* d_in, const int* in_sizes, int n_in,
                              void* d_out, int out_size, void* d_ws, size_t ws_size,
                              hipStream_t stream) {
  const float* logits = (const float*)d_in[0];   // (64, 1024, 512) f32
  const int* targets = (const int*)d_in[1];      // (64, 100) i32
  float* out = (float*)d_out;                    // scalar f32

  float* glp = (float*)d_ws;                     // 64*1024*104 f32
  float* lbArr = glp + (size_t)BB * TT * ROW;    // 64*1024 f32
  float* per = lbArr + (size_t)BB * TT;          // 64 f32

  hipLaunchKernelGGL(k_probs, dim3(BB * TT / 4), dim3(256), 0, stream,
                     logits, targets, glp, lbArr);
  hipLaunchKernelGGL(k_ctc, dim3(BB), dim3(64), 0, stream,
                     glp, lbArr, targets, per);
  hipLaunchKernelGGL(k_mean, dim3(1), dim3(64), 0, stream, per, out);
}

// Round 9
// 69.052 us; speedup vs baseline: 2.8948x; 1.1115x over previous
//
#include <hip/hip_runtime.h>

// CTC loss (blank=0, mean reduction, zero_infinity) for
// B=64, T=1024, K=512, L=100  ->  S = 2L+1 = 201 extended states.
//
// Ratio formulation: factor prod_t p_blank(t) out of all alpha states.
//   even states: a' = sums;  odd states: a' = sums * r  (r = p_lab/p_blank)
//
// Meet-in-the-middle with PER-LANE exponents (round-9):
//   wave 0: forward recursion rows 0..511.  Lane i holds states 4i..4i+3.
//   wave 1: backward (gamma) recursion rows 1023..512, lane-REVERSED so its
//           cross-lane direction is also wave_shr:1 (the DPP primitive
//           verified in rounds 4-7): lane j holds states of i' = 50-j.
//   Each lane rescales LANE-LOCALLY every 4 steps (exact power-of-2, own
//   integer exponent ea); cross-lane terms are scaled by 2^(ea_nbr-ea_self)
//   via a split factor pair f1*f2 recomputed once per window (safe to
//   |dE|<=250; applied (x*f1)*f2 so intermediates can't overflow).
//   Round-8 lesson: wave-level normalization flushes the saddle states
//   (fwd/bwd peaks sit >2^126 from the states carrying the likelihood);
//   per-lane exponents + log-domain combine fix the representation.
//   Combine: per state log2(A)+eaF+log2(G)+eaB -> wave logsumexp.
//   logl/ln2 = logsumexp + sum_t lb(t) - T*9,  lb = log2(512*p_blank).

#define TT 1024
#define BB 64
#define KK 512
#define LL 100
#define ROW 104
#define CH 16                 // rows per chunk

static constexpr float L2E = 1.44269504088896340736f;
static constexpr float LN2 = 0.69314718055994530942f;

// lane i <- lane i-1, lane 0 <- 0.0f  (DPP wave_shr:1, VALU pipe)
__device__ __forceinline__ float dpp_shr1_z(float x) {
  return __builtin_bit_cast(float,
      __builtin_amdgcn_update_dpp(0, __builtin_bit_cast(int, x),
                                  0x138, 0xf, 0xf, true));
}

__device__ __forceinline__ float slog2(float x) {
  return x > 0.0f ? log2f(x) : -1.0e30f;
}

__global__ __launch_bounds__(256) void k_probs(const float* __restrict__ logits,
                                               const int* __restrict__ targets,
                                               float* __restrict__ glp,
                                               float* __restrict__ lbArr) {
  const int wid = threadIdx.x >> 6;
  const int lane = threadIdx.x & 63;
  const int row = (blockIdx.x << 2) + wid;      // row = b*T + t
  const int b = row >> 10;                      // T = 1024
  const float* x = logits + (size_t)row * KK;

  __shared__ float sx[4][KK];

  const float4 v0 = reinterpret_cast<const float4*>(x)[lane];
  const float4 v1 = reinterpret_cast<const float4*>(x)[lane + 64];
  float4* sp = reinterpret_cast<float4*>(sx[wid]);
  sp[lane] = v0;
  sp[lane + 64] = v1;

  float m = fmaxf(fmaxf(fmaxf(v0.x, v0.y), fmaxf(v0.z, v0.w)),
                  fmaxf(fmaxf(v1.x, v1.y), fmaxf(v1.z, v1.w)));
  #pragma unroll
  for (int d = 1; d < 64; d <<= 1) m = fmaxf(m, __shfl_xor(m, d));

  float e = exp2f((v0.x - m) * L2E) + exp2f((v0.y - m) * L2E) +
            exp2f((v0.z - m) * L2E) + exp2f((v0.w - m) * L2E) +
            exp2f((v1.x - m) * L2E) + exp2f((v1.y - m) * L2E) +
            exp2f((v1.z - m) * L2E) + exp2f((v1.w - m) * L2E);
  #pragma unroll
  for (int d = 1; d < 64; d <<= 1) e += __shfl_xor(e, d);

  __syncthreads();
  const float xb = sx[wid][0];                  // blank logit

  if (lane < 52) {
    float2 o = {0.0f, 0.0f};
    if (lane >= 1 && lane <= 50) {
      const int* tg = targets + b * LL + (2 * lane - 2);
      const int2 c = *reinterpret_cast<const int2*>(tg);
      o.x = exp2f((sx[wid][c.x] - xb) * L2E);   // ratio p_lab / p_blank
      o.y = exp2f((sx[wid][c.y] - xb) * L2E);
    }
    reinterpret_cast<float2*>(glp + (size_t)row * ROW)[lane] = o;
  }
  // lb = log2(512 * p_blank) = (xb - m)*log2e + 9 - log2(sum exp)
  if (lane == 0) lbArr[row] = (xb - m) * L2E + 9.0f - log2f(e);
}

__global__ __launch_bounds__(128) void k_ctc(const float* __restrict__ glp,
                                             const float* __restrict__ lbArr,
                                             const int* __restrict__ targets,
                                             float* __restrict__ per) {
  const int b = blockIdx.x;
  const int lane = threadIdx.x & 63;
  const int wv = threadIdx.x >> 6;              // 0 = forward, 1 = backward
  const int* tg = targets + b * LL;

  __shared__ float sG[5][64];                   // g[4 states][lane] + eaB

  float a0 = 0.0f, a1 = 0.0f, a2 = 0.0f, a3 = 0.0f;
  float ea = 0.0f, f1 = 1.0f, f2 = 1.0f;

  // per-lane rescale (every 4 steps) + neighbor exponent factor refresh.
  // All lane-local except one DPP read of the (already updated) neighbor ea.
#define PLRESCALE()                                                        \
  do {                                                                     \
    const float m_ = fmaxf(fmaxf(a0, a1), fmaxf(a2, a3));                  \
    int E_ = (int)((__float_as_uint(m_) >> 23) & 255) - 127;               \
    E_ = (m_ > 0.0f) ? E_ : 0;                                             \
    const float sc_ = __uint_as_float((unsigned)(127 - E_) << 23);         \
    a0 *= sc_; a1 *= sc_; a2 *= sc_; a3 *= sc_;                            \
    ea += (float)E_;                                                       \
    const float ep_ = dpp_shr1_z(ea);                                      \
    const float dE_ = fminf(fmaxf(ep_ - ea, -250.0f), 250.0f);             \
    const float h_ = truncf(dE_ * 0.5f);                                   \
    f1 = exp2f(h_); f2 = exp2f(dE_ - h_);                                  \
  } while (0)

  if (wv == 0) {
    // ---------------- forward: rows 0..511, lane i = states 4i..4i+3 ----
    const int i = lane;
    int offlab = 2 + 2 * i;
    if (offlab > 102) offlab = 102;             // pad lanes -> zeros
    const float* gbase = glp + (size_t)b * TT * ROW + offlab;

    float mA = 0.0f, mB = 0.0f;
    if (i > 0 && 2 * i <= LL - 1) mA = (tg[2 * i] != tg[2 * i - 1]) ? 1.0f : 0.0f;
    if (2 * i + 1 <= LL - 1)      mB = (tg[2 * i + 1] != tg[2 * i]) ? 1.0f : 0.0f;
    a0 = (i == 0) ? 1.0f : 0.0f;                // virtual delta init

    float2 FA[16], FB[16], FC[16];
#define FISSUE(BUF, CHN)                                                   \
    do {                                                                   \
      _Pragma("unroll") for (int j = 0; j < 16; ++j)                       \
        BUF[j] = *reinterpret_cast<const float2*>(                         \
            gbase + (size_t)((CHN) * CH + j) * ROW);                       \
      __builtin_amdgcn_sched_barrier(0);                                   \
    } while (0)
#define FCOMPUTE(BUF)                                                      \
    do {                                                                   \
      _Pragma("unroll") for (int j = 0; j < 16; ++j) {                     \
        const float rx = BUF[j].x, ry = BUF[j].y;                          \
        const float A3 = dpp_shr1_z(a3) * f1 * f2;  /* scaled neighbor */  \
        const float n0 = a0 + A3;                                          \
        const float n1 = (a0 + a1 + mA * A3) * rx;                         \
        const float n2 = a1 + a2;                                          \
        const float n3 = (a2 + a3 + mB * a1) * ry;                         \
        a0 = n0; a1 = n1; a2 = n2; a3 = n3;                                \
        if ((j & 3) == 3) PLRESCALE();                                     \
      }                                                                    \
    } while (0)

    FISSUE(FA, 0);
    FISSUE(FB, 1);
    for (int c = 0; c < 30; c += 3) {
      FISSUE(FC, c + 2); FCOMPUTE(FA);
      FISSUE(FA, c + 3); FCOMPUTE(FB);
      FISSUE(FB, c + 4); FCOMPUTE(FC);
    }
    FCOMPUTE(FA);                               // chunk 30
    FCOMPUTE(FB);                               // chunk 31
#undef FISSUE
#undef FCOMPUTE
  } else {
    // ------- backward: rows 1023..512, lane j = states of i' = 50-j -----
    // g_t[s] = q[s]g[s] + q[s+1]g[s+1] + skip[s+2]q[s+2]g[s+2]; states s+4,
    // s+5 live on lane j-1  ->  cross-lane via the same wave_shr:1 DPP.
    const int ii = 50 - lane;                   // i' (may be negative: pad)
    int offlab = 2 + 2 * ii;
    if (offlab < 0) offlab = 0;                 // pads read row[0..2] = 0,0,r[0]
    const float* gbase = glp + (size_t)b * TT * ROW + offlab;

    float mB = 0.0f, mAn = 0.0f;
    if (ii >= 0 && 2 * ii + 1 <= LL - 1)
      mB = (tg[2 * ii + 1] != tg[2 * ii]) ? 1.0f : 0.0f;
    if (ii >= 0 && ii <= 48)
      mAn = (tg[2 * ii + 2] != tg[2 * ii + 1]) ? 1.0f : 0.0f;
    if (lane == 1) a3 = 1.0f;                   // state 199 (ii = 49)
    if (lane == 0) a0 = 1.0f;                   // state 200 (ii = 50)

    float3 GA[16], GB[16], GC[16];
#define BISSUE(BUF, CHN)                                                   \
    do {                                                                   \
      _Pragma("unroll") for (int j = 0; j < 16; ++j)                       \
        BUF[j] = *reinterpret_cast<const float3*>(                         \
            gbase + (size_t)(1023 - ((CHN) * CH + j)) * ROW);              \
      __builtin_amdgcn_sched_barrier(0);                                   \
    } while (0)
#define BCOMPUTE(BUF)                                                      \
    do {                                                                   \
      _Pragma("unroll") for (int j = 0; j < 16; ++j) {                     \
        const float r0 = BUF[j].x, r1 = BUF[j].y, r2 = BUF[j].z;           \
        const float G0 = dpp_shr1_z(a0) * f1 * f2;  /* g[4i'+4] scaled */  \
        const float G1 = dpp_shr1_z(a1) * f1 * f2;  /* g[4i'+5] scaled */  \
        const float u = r0 * a1;                                           \
        const float v = r1 * a3;                                           \
        const float n0 = a0 + u;                                           \
        const float n1 = u + fmaf(mB, v, a2);                              \
        const float n2 = a2 + v;                                           \
        const float n3 = v + fmaf(mAn, r2 * G1, G0);                       \
        a0 = n0; a1 = n1; a2 = n2; a3 = n3;                                \
        if ((j & 3) == 3) PLRESCALE();                                     \
      }                                                                    \
    } while (0)

    BISSUE(GA, 0);
    BISSUE(GB, 1);
    for (int c = 0; c < 30; c += 3) {
      BISSUE(GC, c + 2); BCOMPUTE(GA);
      BISSUE(GA, c + 3); BCOMPUTE(GB);
      BISSUE(GB, c + 4); BCOMPUTE(GC);
    }
    BCOMPUTE(GA);                               // chunk 30
    BCOMPUTE(GB);                               // chunk 31
#undef BISSUE
#undef BCOMPUTE

    sG[0][lane] = a0; sG[1][lane] = a1; sG[2][lane] = a2; sG[3][lane] = a3;
    sG[4][lane] = ea;
  }
#undef PLRESCALE

  __syncthreads();                              // backward publishes sG

  if (wv == 0) {
    const int i = lane;
    // G's states 4i..4i+3 live on backward lane 50-i (63 = all-zero pad).
    const int gj = (i <= 50) ? (50 - i) : 63;
    const float eb = sG[4][gj];
    // per-state log2(A*G) with per-lane exponents; wave logsumexp.
    float w0 = slog2(a0) + ea + slog2(sG[0][gj]) + eb;
    float w1 = slog2(a1) + ea + slog2(sG[1][gj]) + eb;
    float w2 = slog2(a2) + ea + slog2(sG[2][gj]) + eb;
    float w3 = slog2(a3) + ea + slog2(sG[3][gj]) + eb;
    float wm = fmaxf(fmaxf(w0, w1), fmaxf(w2, w3));
    #pragma unroll
    for (int d = 1; d < 64; d <<= 1) wm = fmaxf(wm, __shfl_xor(wm, d));
    float ss = exp2f(w0 - wm) + exp2f(w1 - wm) +
               exp2f(w2 - wm) + exp2f(w3 - wm);
    #pragma unroll
    for (int d = 1; d < 64; d <<= 1) ss += __shfl_xor(ss, d);

    // sum lb over all 1024 rows (coalesced float4 reads)
    float s4 = 0.0f;
    const float4* lbv = reinterpret_cast<const float4*>(lbArr + (size_t)b * TT);
    #pragma unroll
    for (int j = 0; j < 4; ++j) {
      const float4 v = lbv[i + 64 * j];
      s4 += (v.x + v.y) + (v.z + v.w);
    }
    #pragma unroll
    for (int d = 1; d < 64; d <<= 1) s4 += __shfl_xor(s4, d);

    if (i == 0) {
      float loss = 0.0f;                        // zero_infinity
      if (wm > -1.0e29f) {
        const float logl2 = wm + log2f(ss) + s4 - (float)(TT * 9);
        loss = -(logl2 * LN2) / (float)LL;
      }
      per[b] = loss;
    }
  }
}

__global__ __launch_bounds__(64) void k_mean(const float* __restrict__ per,
                                             float* __restrict__ out) {
  const int i = threadIdx.x;
  float v = per[i];
  #pragma unroll
  for (int d = 1; d < 64; d <<= 1) v += __shfl_xor(v, d);
  if (i == 0) out[0] = v * (1.0f / (float)BB);
}

extern "C" void kernel_launch(void* const* d_in, const int* in_sizes, int n_in,
                              void* d_out, int out_size, void* d_ws, size_t ws_size,
                              hipStream_t stream) {
  const float* logits = (const float*)d_in[0];   // (64, 1024, 512) f32
  const int* targets = (const int*)d_in[1];      // (64, 100) i32
  float* out = (float*)d_out;                    // scalar f32

  float* glp = (float*)d_ws;                     // 64*1024*104 f32
  float* lbArr = glp + (size_t)BB * TT * ROW;    // 64*1024 f32
  float* per = lbArr + (size_t)BB * TT;          // 64 f32

  hipLaunchKernelGGL(k_probs, dim3(BB * TT / 4), dim3(256), 0, stream,
                     logits, targets, glp, lbArr);
  hipLaunchKernelGGL(k_ctc, dim3(BB), dim3(128), 0, stream,
                     glp, lbArr, targets, per);
  hipLaunchKernelGGL(k_mean, dim3(1), dim3(64), 0, stream, per, out);
}